// Round 16
// baseline (525.110 us; speedup 1.0000x reference)
//
#include <hip/hip_runtime.h>
#include <math.h>

#define B_ 32
#define NODES_ 512
#define IN_ 256
#define OUT_ 128
#define CAPS_ 16
#define KW_ 5
#define M_ (B_*NODES_)            // 16384
#define N_ (KW_*OUT_)             // 640
#define NCH 32                    // node chunks of 16

typedef __attribute__((ext_vector_type(8))) short short8;
typedef __attribute__((ext_vector_type(4))) float f32x4;

// ---- workspace layout (bytes) ----
#define Y_BOFF   0
#define CTR_BOFF 41943040         // barrier counters (was logits; 1 KB)
#define V_BOFF   42991616
#define SP_BOFF  43253760
#define BT_SZ    (N_*IN_*2)       // 327,680 bytes each

__device__ __forceinline__ float b2f(unsigned short u) {
  union { unsigned int i; float f; } c; c.i = ((unsigned int)u) << 16; return c.f;
}
__device__ __forceinline__ unsigned short f2b(float f) {
  union { float f; unsigned int i; } c; c.f = f;
  unsigned int u = c.i;
  u += 0x7fffu + ((u >> 16) & 1u);
  return (unsigned short)(u >> 16);
}
__device__ __forceinline__ void async_load16(const void* g, void* l) {
  __builtin_amdgcn_global_load_lds(
      (const __attribute__((address_space(1))) unsigned int*)g,
      (__attribute__((address_space(3))) unsigned int*)l, 16, 0, 0);
}

// 16-block per-batch barrier: arrival count + spin (device-scope L2).
__device__ __forceinline__ void batch_bar(int* c) {
  __syncthreads();
  if (threadIdx.x == 0) {
    __threadfence();                       // release: s_part/v visible
    atomicAdd(c, 1);
    while (atomicAdd(c, 0) < 16) {}       // device-scope fresh load
  }
  __syncthreads();
  __threadfence();                         // acquire: invalidate stale L1
}

// ============================================================
// conv_w: split W into K-MAJOR bf16 hi/lo panels.
// ============================================================
__global__ __launch_bounds__(256) void conv_w(const float* __restrict__ W,
                                              unsigned short* __restrict__ bThi,
                                              unsigned short* __restrict__ bTlo) {
  int n = blockIdx.x;           // 0..639
  int i = threadIdx.x;          // 0..255
  int k = n >> 7, o = n & 127;
  float v = W[((size_t)k*IN_ + i)*OUT_ + o];
  unsigned short h = f2b(v);
  size_t dst = ((size_t)(i >> 3)*N_ + n)*8 + (i & 7);
  bThi[dst] = h;
  bTlo[dst] = f2b(v - b2f(h));
}

// ============================================================
// gemm_fn (R10-proven, ~11us): FULL-N blocks, coalesced reg-staged A,
// flat gload_lds B panels, split-bf16 3-pass MFMA.
// ============================================================
__global__ __launch_bounds__(512) void gemm_fn(const float* __restrict__ x,
                                               const unsigned short* __restrict__ bThi,
                                               const unsigned short* __restrict__ bTlo,
                                               float* __restrict__ y) {
  __shared__ float A_lds[8*64*4];      //  8 KB [cg][row][4f]
  __shared__ short Bh_lds[4*640*8];    // 40 KB [kg][n][8]
  __shared__ short Bl_lds[4*640*8];    // 40 KB
  const int t    = threadIdx.x;
  const int w    = t >> 6;
  const int lane = t & 63;
  const int lrow = lane & 15;
  const int lk   = lane >> 4;
  const int m0   = blockIdx.x * 64;
  const int wn0  = w * 80;
  const int arow = t >> 3;
  const int ac4  = t & 7;

  f32x4 acc[4][5];
  #pragma unroll
  for (int i=0;i<4;++i)
    #pragma unroll
    for (int j=0;j<5;++j) acc[i][j] = (f32x4){0.f,0.f,0.f,0.f};

  for (int kbi = 0; kbi < 8; ++kbi) {
    const int kb = kbi*32;
    const unsigned short* bh_src = bThi + (size_t)kbi*4*N_*8;
    const unsigned short* bl_src = bTlo + (size_t)kbi*4*N_*8;
    #pragma unroll
    for (int q=0; q<5; ++q) {
      int db = q*512 + w*64;
      async_load16(bh_src + (size_t)(db + lane)*8, &Bh_lds[db*8]);
      async_load16(bl_src + (size_t)(db + lane)*8, &Bl_lds[db*8]);
    }
    {
      float4 av = *(const float4*)(x + (size_t)(m0 + arow)*IN_ + kb + ac4*4);
      *(float4*)&A_lds[((ac4*64) + arow)*4] = av;
    }
    __syncthreads();

    short8 ah[4], al[4];
    #pragma unroll
    for (int mi=0; mi<4; ++mi) {
      int row = mi*16 + lrow;
      f32x4 a0 = *(const f32x4*)&A_lds[((2*lk  )*64 + row)*4];
      f32x4 a1 = *(const f32x4*)&A_lds[((2*lk+1)*64 + row)*4];
      #pragma unroll
      for (int j=0; j<8; ++j) {
        float f = (j < 4) ? a0[j] : a1[j-4];
        unsigned short h = f2b(f);
        ah[mi][j] = (short)h;
        al[mi][j] = (short)f2b(f - b2f(h));
      }
    }
    #pragma unroll
    for (int ni=0; ni<5; ++ni) {
      int nb = wn0 + ni*16 + lrow;
      short8 bh = *(const short8*)&Bh_lds[(lk*N_ + nb)*8];
      short8 bl = *(const short8*)&Bl_lds[(lk*N_ + nb)*8];
      #pragma unroll
      for (int mi=0; mi<4; ++mi) {
        acc[mi][ni] = __builtin_amdgcn_mfma_f32_16x16x32_bf16(bh, ah[mi], acc[mi][ni], 0, 0, 0);
        acc[mi][ni] = __builtin_amdgcn_mfma_f32_16x16x32_bf16(bh, al[mi], acc[mi][ni], 0, 0, 0);
        acc[mi][ni] = __builtin_amdgcn_mfma_f32_16x16x32_bf16(bl, ah[mi], acc[mi][ni], 0, 0, 0);
      }
    }
    __syncthreads();
  }

  #pragma unroll
  for (int mi=0; mi<4; ++mi) {
    int m = m0 + mi*16 + lrow;
    #pragma unroll
    for (int ni=0; ni<5; ++ni) {
      int nb = wn0 + ni*16 + lk*4;
      float4 o = {acc[mi][ni][0], acc[mi][ni][1], acc[mi][ni][2], acc[mi][ni][3]};
      *(float4*)(y + (size_t)m*N_ + nb) = o;
    }
  }
}

// ============================================================
// route_batch: ALL 4 routing sweeps + squashes in ONE kernel.
// 512 blocks x 256 thr, 55 KB LDS -> exactly 2 blocks/CU, all
// co-resident. Block bx owns batch b=bx>>4, chunks {2cp,2cp+1}.
// Inter-block deps are WITHIN-BATCH only -> 16-block atomic
// barrier replaces grid.sync (R14: 80us/sync) and kernel launches.
// Logits in 2 registers all sweeps. Phase bodies = R8-proven math.
// ============================================================
__global__ __launch_bounds__(256) void route_batch(const float* __restrict__ y,
                                                   const float* __restrict__ alpha,
                                                   const float* __restrict__ contrib,
                                                   float* __restrict__ v,
                                                   float* __restrict__ s_part,
                                                   float* __restrict__ out,
                                                   int* __restrict__ ctr) {
  __shared__ __align__(16) float sh_y[16*640];      // 40 KB
  __shared__ __align__(16) float sh_v[16*132];      //  8.4 KB
  __shared__ __align__(16) float sh_alpha[16*16*5]; //  5 KB
  __shared__ float sh_logit[16][16];                // cw
  __shared__ float sh_red[256];
  __shared__ float sh_ss[2];

  const int t    = threadIdx.x;
  const int bx   = blockIdx.x;    // 0..511
  const int b    = bx >> 4;       // 0..31
  const int cp   = bx & 15;       // 0..15
  const int node = t >> 4, cap = t & 15;
  int* bctr = ctr + b*8;          // 8 barrier slots per batch

  float lreg[2];
  #pragma unroll
  for (int hh=0; hh<2; ++hh)
    lreg[hh] = contrib[(size_t)b*NODES_ + (cp*2+hh)*16 + node];

  for (int it = 0; it < 4; ++it) {
    if (it >= 1) {
      const float* vbase = v + (size_t)b*CAPS_*OUT_;
      #pragma unroll
      for (int q=0; q<2; ++q) {
        int flat = (t + q*256)*4;
        int c = flat >> 7, o = flat & 127;
        float4 vv = *(const float4*)(vbase + flat);
        *(float4*)&sh_v[c*132 + o] = vv;
      }
    }

    #pragma unroll
    for (int hh=0; hh<2; ++hh) {
      const int ch = cp*2 + hh;
      const int n0 = ch*16;

      const float* ybase = y + ((size_t)(b*NODES_ + n0))*N_;
      #pragma unroll
      for (int q=0; q<10; ++q) {
        int d0 = q*256 + (t & ~63);
        async_load16(ybase + (size_t)(d0 + (t & 63))*4, &sh_y[d0*4]);
      }
      const float* abase = alpha + (size_t)n0*CAPS_*KW_;
      for (int i = t; i < 320; i += 256) {
        float4 av = *(const float4*)(abase + i*4);
        *(float4*)&sh_alpha[i*4] = av;
      }
      __syncthreads();   // drains async y + LDS writes

      if (it >= 1) {
        // ---- phase 1: a[node][cap] = sum_o u*v (R8 body) ----
        const float* al = &sh_alpha[(node*16+cap)*5];
        float a0=al[0],a1=al[1],a2=al[2],a3=al[3],a4=al[4];
        const float* yb = &sh_y[node*640];
        const float* vb = &sh_v[cap*132];
        float accd = 0.f;
        #pragma unroll 4
        for (int o=0; o<128; o+=4) {
          float4 y0 = *(const float4*)(yb + 0*128 + o);
          float4 y1 = *(const float4*)(yb + 1*128 + o);
          float4 y2 = *(const float4*)(yb + 2*128 + o);
          float4 y3 = *(const float4*)(yb + 3*128 + o);
          float4 y4 = *(const float4*)(yb + 4*128 + o);
          float4 vv = *(const float4*)(vb + o);
          float ux = a0*y0.x + a1*y1.x + a2*y2.x + a3*y3.x + a4*y4.x;
          float uy = a0*y0.y + a1*y1.y + a2*y2.y + a3*y3.y + a4*y4.y;
          float uz = a0*y0.z + a1*y1.z + a2*y2.z + a3*y3.z + a4*y4.z;
          float uw = a0*y0.w + a1*y1.w + a2*y2.w + a3*y3.w + a4*y4.w;
          accd += ux*vv.x + uy*vv.y + uz*vv.z + uw*vv.w;
        }
        float newl = lreg[hh] + accd;
        lreg[hh] = newl;
        // softmax over caps: lanes 0-15 = caps of one node
        float m = newl;
        m = fmaxf(m, __shfl_xor(m, 1, 64));
        m = fmaxf(m, __shfl_xor(m, 2, 64));
        m = fmaxf(m, __shfl_xor(m, 4, 64));
        m = fmaxf(m, __shfl_xor(m, 8, 64));
        float e = __expf(newl - m);
        float ssum = e;
        ssum += __shfl_xor(ssum, 1, 64);
        ssum += __shfl_xor(ssum, 2, 64);
        ssum += __shfl_xor(ssum, 4, 64);
        ssum += __shfl_xor(ssum, 8, 64);
        sh_logit[node][cap] = e / ssum;
      } else {
        sh_logit[node][cap] = 0.0625f;
      }
      __syncthreads();

      // ---- phase 2: s_part[c][o] = sum_nd cw*u (R8 body, c fast) ----
      float* spb = s_part + ((size_t)(b*NCH + ch))*CAPS_*OUT_;
      #pragma unroll
      for (int sl=0; sl<2; ++sl) {
        int slot = t + sl*256;
        int c  = slot & 15;
        int o  = (slot >> 4) * 4;
        float4 acc = {0.f,0.f,0.f,0.f};
        #pragma unroll 4
        for (int nd=0; nd<16; ++nd) {
          const float* al2 = &sh_alpha[(nd*16+c)*5];
          float a0=al2[0],a1=al2[1],a2=al2[2],a3=al2[3],a4=al2[4];
          const float* yb2 = &sh_y[nd*640 + o];
          float4 y0 = *(const float4*)(yb2);
          float4 y1 = *(const float4*)(yb2 + 128);
          float4 y2 = *(const float4*)(yb2 + 256);
          float4 y3 = *(const float4*)(yb2 + 384);
          float4 y4 = *(const float4*)(yb2 + 512);
          float cw = sh_logit[nd][c];
          acc.x += cw*(a0*y0.x + a1*y1.x + a2*y2.x + a3*y3.x + a4*y4.x);
          acc.y += cw*(a0*y0.y + a1*y1.y + a2*y2.y + a3*y3.y + a4*y4.y);
          acc.z += cw*(a0*y0.z + a1*y1.z + a2*y2.z + a3*y3.z + a4*y4.z);
          acc.w += cw*(a0*y0.w + a1*y1.w + a2*y2.w + a3*y3.w + a4*y4.w);
        }
        *(float4*)(spb + c*OUT_ + o) = acc;
      }
      __syncthreads();   // sh_y/sh_alpha reuse by next half
    }

    // ---- barrier A: all batch-b s_part written ----
    batch_bar(&bctr[it*2]);

    // ---- squash: this block reduces (b, c=cp) (R14-proven body) ----
    {
      const int o = t & 127, h = t >> 7;
      const float* sp = s_part + ((size_t)(b*NCH + h*16)*CAPS_ + cp)*OUT_ + o;
      float part = 0.f;
      #pragma unroll
      for (int cc=0; cc<16; ++cc) part += sp[(size_t)cc*CAPS_*OUT_];
      sh_red[h*128 + o] = part;
      __syncthreads();
      float s = 0.f;
      if (t < 128) {
        s = sh_red[t] + sh_red[128 + t];
        float ss = s*s;
        #pragma unroll
        for (int off=32; off>0; off>>=1) ss += __shfl_down(ss, off, 64);
        if ((t & 63) == 0) sh_ss[t>>6] = ss;
      }
      __syncthreads();
      if (t < 128) {
        float sn = sh_ss[0] + sh_ss[1];
        float scale = (sn/(1.f+sn)) / (sqrtf(sn)+1e-8f);
        float* dst = (it==3) ? out : v;
        dst[((size_t)b*CAPS_ + cp)*OUT_ + t] = scale*s;
      }
    }
    // ---- barrier B: v visible to all batch-b blocks ----
    if (it < 3) batch_bar(&bctr[it*2+1]);
  }
}

// ============================================================
extern "C" void kernel_launch(void* const* d_in, const int* in_sizes, int n_in,
                              void* d_out, int out_size, void* d_ws, size_t ws_size,
                              hipStream_t stream) {
  const float* x       = (const float*)d_in[0];
  const float* contrib = (const float*)d_in[1];
  const float* W       = (const float*)d_in[2];
  const float* alpha   = (const float*)d_in[3];
  float* out = (float*)d_out;
  char*  wsb = (char*)d_ws;

  float* y             = (float*)(wsb + Y_BOFF);
  int*   ctr           = (int*)(wsb + CTR_BOFF);
  float* v             = (float*)(wsb + V_BOFF);
  float* s_part        = (float*)(wsb + SP_BOFF);
  // bT hi/lo alias the s_part region (consumed before s_part first written)
  unsigned short* bThi = (unsigned short*)(wsb + SP_BOFF);
  unsigned short* bTlo = (unsigned short*)(wsb + SP_BOFF + BT_SZ);

  conv_w<<<N_, 256, 0, stream>>>(W, bThi, bTlo);
  gemm_fn<<<M_/64, 512, 0, stream>>>(x, bThi, bTlo, y);

  // zero the 32x8 barrier counters each launch (deterministic replays)
  hipMemsetAsync(ctr, 0, 32*8*sizeof(int), stream);

  route_batch<<<512, 256, 0, stream>>>(y, alpha, contrib, v, s_part, out, ctr);
}

// Round 17
// 137.884 us; speedup vs baseline: 3.8084x; 3.8084x over previous
//
#include <hip/hip_runtime.h>
#include <math.h>

#define B_ 32
#define NODES_ 512
#define IN_ 256
#define OUT_ 128
#define CAPS_ 16
#define KW_ 5
#define M_ (B_*NODES_)            // 16384
#define N_ (KW_*OUT_)             // 640
#define NCH 32                    // node chunks of 16

typedef __attribute__((ext_vector_type(8))) short short8;
typedef __attribute__((ext_vector_type(4))) float f32x4;

// ---- workspace layout (bytes) ---- (round-5 proven: 51,642,368 total)
#define Y_BOFF   0
#define L_BOFF   41943040
#define V_BOFF   42991616
#define SP_BOFF  43253760
#define BT_SZ    (N_*IN_*2)       // 327,680 bytes each

#define YPAD 648                  // 648%32==8 -> 4 node-groups on disjoint bank octets

__device__ __forceinline__ float b2f(unsigned short u) {
  union { unsigned int i; float f; } c; c.i = ((unsigned int)u) << 16; return c.f;
}
__device__ __forceinline__ unsigned short f2b(float f) {
  union { float f; unsigned int i; } c; c.f = f;
  unsigned int u = c.i;
  u += 0x7fffu + ((u >> 16) & 1u);
  return (unsigned short)(u >> 16);
}
__device__ __forceinline__ void async_load16(const void* g, void* l) {
  __builtin_amdgcn_global_load_lds(
      (const __attribute__((address_space(1))) unsigned int*)g,
      (__attribute__((address_space(3))) unsigned int*)l, 16, 0, 0);
}

// ============================================================
// conv_w: split W into K-MAJOR bf16 hi/lo panels.
// ============================================================
__global__ __launch_bounds__(256) void conv_w(const float* __restrict__ W,
                                              unsigned short* __restrict__ bThi,
                                              unsigned short* __restrict__ bTlo) {
  int n = blockIdx.x;           // 0..639
  int i = threadIdx.x;          // 0..255
  int k = n >> 7, o = n & 127;
  float v = W[((size_t)k*IN_ + i)*OUT_ + o];
  unsigned short h = f2b(v);
  size_t dst = ((size_t)(i >> 3)*N_ + n)*8 + (i & 7);
  bThi[dst] = h;
  bTlo[dst] = f2b(v - b2f(h));
}

// ============================================================
// gemm_fn (R10-proven, ~11us): FULL-N blocks, coalesced reg-staged A,
// flat gload_lds B panels, split-bf16 3-pass MFMA.
// ============================================================
__global__ __launch_bounds__(512) void gemm_fn(const float* __restrict__ x,
                                               const unsigned short* __restrict__ bThi,
                                               const unsigned short* __restrict__ bTlo,
                                               float* __restrict__ y) {
  __shared__ float A_lds[8*64*4];      //  8 KB [cg][row][4f]
  __shared__ short Bh_lds[4*640*8];    // 40 KB [kg][n][8]
  __shared__ short Bl_lds[4*640*8];    // 40 KB
  const int t    = threadIdx.x;
  const int w    = t >> 6;
  const int lane = t & 63;
  const int lrow = lane & 15;
  const int lk   = lane >> 4;
  const int m0   = blockIdx.x * 64;
  const int wn0  = w * 80;
  const int arow = t >> 3;
  const int ac4  = t & 7;

  f32x4 acc[4][5];
  #pragma unroll
  for (int i=0;i<4;++i)
    #pragma unroll
    for (int j=0;j<5;++j) acc[i][j] = (f32x4){0.f,0.f,0.f,0.f};

  for (int kbi = 0; kbi < 8; ++kbi) {
    const int kb = kbi*32;
    const unsigned short* bh_src = bThi + (size_t)kbi*4*N_*8;
    const unsigned short* bl_src = bTlo + (size_t)kbi*4*N_*8;
    #pragma unroll
    for (int q=0; q<5; ++q) {
      int db = q*512 + w*64;
      async_load16(bh_src + (size_t)(db + lane)*8, &Bh_lds[db*8]);
      async_load16(bl_src + (size_t)(db + lane)*8, &Bl_lds[db*8]);
    }
    {
      float4 av = *(const float4*)(x + (size_t)(m0 + arow)*IN_ + kb + ac4*4);
      *(float4*)&A_lds[((ac4*64) + arow)*4] = av;
    }
    __syncthreads();

    short8 ah[4], al[4];
    #pragma unroll
    for (int mi=0; mi<4; ++mi) {
      int row = mi*16 + lrow;
      f32x4 a0 = *(const f32x4*)&A_lds[((2*lk  )*64 + row)*4];
      f32x4 a1 = *(const f32x4*)&A_lds[((2*lk+1)*64 + row)*4];
      #pragma unroll
      for (int j=0; j<8; ++j) {
        float f = (j < 4) ? a0[j] : a1[j-4];
        unsigned short h = f2b(f);
        ah[mi][j] = (short)h;
        al[mi][j] = (short)f2b(f - b2f(h));
      }
    }
    #pragma unroll
    for (int ni=0; ni<5; ++ni) {
      int nb = wn0 + ni*16 + lrow;
      short8 bh = *(const short8*)&Bh_lds[(lk*N_ + nb)*8];
      short8 bl = *(const short8*)&Bl_lds[(lk*N_ + nb)*8];
      #pragma unroll
      for (int mi=0; mi<4; ++mi) {
        acc[mi][ni] = __builtin_amdgcn_mfma_f32_16x16x32_bf16(bh, ah[mi], acc[mi][ni], 0, 0, 0);
        acc[mi][ni] = __builtin_amdgcn_mfma_f32_16x16x32_bf16(bh, al[mi], acc[mi][ni], 0, 0, 0);
        acc[mi][ni] = __builtin_amdgcn_mfma_f32_16x16x32_bf16(bl, ah[mi], acc[mi][ni], 0, 0, 0);
      }
    }
    __syncthreads();
  }

  #pragma unroll
  for (int mi=0; mi<4; ++mi) {
    int m = m0 + mi*16 + lrow;
    #pragma unroll
    for (int ni=0; ni<5; ++ni) {
      int nb = wn0 + ni*16 + lk*4;
      float4 o = {acc[mi][ni][0], acc[mi][ni][1], acc[mi][ni][2], acc[mi][ni][3]};
      *(float4*)(y + (size_t)m*N_ + nb) = o;
    }
  }
}

// ============================================================
// route_rs: restructured routing sweep (16-node chunk, 256 thr).
// LDS-instr-bound fix: wave lanes read DISTINCT y data.
// P1: thread=(node, o-octet): 62 b128/thread (was 192); shfl
//     butterfly over o-lanes; softmax = 16-lane butterfly.
// P2: thread=(o-quad, cap-octet, nd-quartet): 60 b128 (was 160);
//     cross-wave nd-reduce via red buffer overlaid on sh_y.
// alpha staged TRANSPOSED [nd][k][c]; cwa = cw*aT per chunk.
// ============================================================
__global__ __launch_bounds__(256) void route_rs(const float* __restrict__ y,
                                                const float* __restrict__ alpha,
                                                const float* __restrict__ contrib,
                                                float* __restrict__ logits,
                                                const float* __restrict__ vin,
                                                float* __restrict__ s_part,
                                                int mode) {
  __shared__ __align__(16) float sh_y[16*YPAD];   // 41.5 KB (red overlay after P2)
  __shared__ __align__(16) float sh_v[16*132];    //  8.4 KB [cap][o]
  __shared__ __align__(16) float sh_aT[16*80];    //  5 KB  [nd][k*16+c]
  __shared__ __align__(16) float sh_cwa[16*80];   //  5 KB  [nd][k*16+c]
  __shared__ float sh_cw[256];                    //  1 KB  [nd*16+c]

  const int t  = threadIdx.x;
  const int ch = blockIdx.x;   // 0..31
  const int b  = blockIdx.y;   // 0..31
  const int n0 = ch*16;

  // ---- stage y: reg round-trip into padded rows (R11-proven) ----
  const float* ybase = y + ((size_t)(b*NODES_ + n0))*N_;
  float4 yst[10];
  #pragma unroll
  for (int q=0; q<10; ++q) yst[q] = *(const float4*)(ybase + (size_t)(t + q*256)*4);
  #pragma unroll
  for (int q=0; q<10; ++q) {
    int flat = (t + q*256)*4;
    int nd   = flat / 640;
    int rem  = flat - nd*640;
    *(float4*)&sh_y[nd*YPAD + rem] = yst[q];
  }
  // ---- stage alpha TRANSPOSED: aT[nd][k*16+c] = alpha[n0+nd][c][k] ----
  const float* abase = alpha + (size_t)n0*CAPS_*KW_;
  for (int i = t; i < 320; i += 256) {
    float4 av = *(const float4*)(abase + i*4);
    int flat = i*4;
    int nd   = flat / 80;
    int rem  = flat - nd*80;        // rem..rem+3 stay within this nd (80%4==0)
    #pragma unroll
    for (int e=0; e<4; ++e) {
      int r = rem + e;
      int c = r / 5;
      int k = r - c*5;
      sh_aT[nd*80 + k*16 + c] = av[e];
    }
  }
  if (mode >= 1) {
    const float* vbase = vin + (size_t)b*CAPS_*OUT_;
    #pragma unroll
    for (int q=0; q<2; ++q) {
      int flat = (t + q*256)*4;
      int c = flat >> 7, o = flat & 127;
      float4 vv = *(const float4*)(vbase + flat);
      *(float4*)&sh_v[c*132 + o] = vv;
    }
  } else {
    sh_cw[t] = 0.0625f;
    int nd = t >> 4, c = t & 15;
    logits[((size_t)b*CAPS_ + c)*NODES_ + n0 + nd] = contrib[(size_t)b*NODES_ + n0 + nd];
  }
  __syncthreads();

  if (mode >= 1) {
    // ---- phase 1: thread = (nd = t>>4, og = t&15), o-range og*8..+7 ----
    const int nd = t >> 4, og = t & 15;
    float4 yq[5][2];
    #pragma unroll
    for (int k=0; k<5; ++k) {
      yq[k][0] = *(const float4*)&sh_y[nd*YPAD + k*128 + og*8];
      yq[k][1] = *(const float4*)&sh_y[nd*YPAD + k*128 + og*8 + 4];
    }
    float p[16];
    #pragma unroll
    for (int c=0;c<16;++c) p[c] = 0.f;
    #pragma unroll
    for (int cq=0; cq<4; ++cq) {
      float4 a5[5];
      #pragma unroll
      for (int k=0;k<5;++k) a5[k] = *(const float4*)&sh_aT[nd*80 + k*16 + cq*4];
      #pragma unroll
      for (int cl=0; cl<4; ++cl) {
        int c = cq*4 + cl;
        float4 v0 = *(const float4*)&sh_v[c*132 + og*8];
        float4 v1 = *(const float4*)&sh_v[c*132 + og*8 + 4];
        float d[5];
        #pragma unroll
        for (int k=0;k<5;++k) {
          d[k] = yq[k][0].x*v0.x + yq[k][0].y*v0.y + yq[k][0].z*v0.z + yq[k][0].w*v0.w
               + yq[k][1].x*v1.x + yq[k][1].y*v1.y + yq[k][1].z*v1.z + yq[k][1].w*v1.w;
        }
        p[c] += a5[0][cl]*d[0] + a5[1][cl]*d[1] + a5[2][cl]*d[2]
              + a5[3][cl]*d[3] + a5[4][cl]*d[4];
      }
    }
    // butterfly all-reduce over the 16 og-lanes (lane bits 0..3)
    #pragma unroll
    for (int c=0;c<16;++c) {
      p[c] += __shfl_xor(p[c], 1, 64);
      p[c] += __shfl_xor(p[c], 2, 64);
      p[c] += __shfl_xor(p[c], 4, 64);
      p[c] += __shfl_xor(p[c], 8, 64);
    }
    // lane og owns cap c==og (static select)
    float mine = 0.f;
    #pragma unroll
    for (int c=0;c<16;++c) mine = (og == c) ? p[c] : mine;
    float lold = logits[((size_t)b*CAPS_ + og)*NODES_ + n0 + nd];
    float newl = lold + mine;
    logits[((size_t)b*CAPS_ + og)*NODES_ + n0 + nd] = newl;
    // softmax over caps (= og lanes of same nd)
    float m = newl;
    m = fmaxf(m, __shfl_xor(m, 1, 64));
    m = fmaxf(m, __shfl_xor(m, 2, 64));
    m = fmaxf(m, __shfl_xor(m, 4, 64));
    m = fmaxf(m, __shfl_xor(m, 8, 64));
    float e = __expf(newl - m);
    float ssum = e;
    ssum += __shfl_xor(ssum, 1, 64);
    ssum += __shfl_xor(ssum, 2, 64);
    ssum += __shfl_xor(ssum, 4, 64);
    ssum += __shfl_xor(ssum, 8, 64);
    sh_cw[nd*16 + og] = e / ssum;
  }
  __syncthreads();

  // ---- cwa[nd][k*16+c] = cw[nd][c] * aT ----
  #pragma unroll
  for (int i = t; i < 1280; i += 256) {
    int nd = i / 80;
    int c  = i & 15;               // i%80's low 4 bits == c (16 | 80 layout)
    sh_cwa[i] = sh_cw[nd*16 + c] * sh_aT[i];
  }
  __syncthreads();

  // ---- phase 2: thread = (oq = t&31, cg = (t>>5)&1, ng = t>>6) ----
  {
    const int oq = t & 31;
    const int cg = (t >> 5) & 1;
    const int ng = t >> 6;          // wave id; nds {ng, ng+4, ng+8, ng+12}
    float acc[8][4];
    #pragma unroll
    for (int j=0;j<8;++j)
      #pragma unroll
      for (int oo=0;oo<4;++oo) acc[j][oo] = 0.f;

    #pragma unroll
    for (int ii=0; ii<4; ++ii) {
      int nd = ng + ii*4;
      #pragma unroll
      for (int k=0; k<5; ++k) {
        float4 yq  = *(const float4*)&sh_y[nd*YPAD + k*128 + oq*4];
        float4 ca0 = *(const float4*)&sh_cwa[nd*80 + k*16 + cg*8];
        float4 ca1 = *(const float4*)&sh_cwa[nd*80 + k*16 + cg*8 + 4];
        float cav[8] = {ca0.x,ca0.y,ca0.z,ca0.w,ca1.x,ca1.y,ca1.z,ca1.w};
        float yv[4]  = {yq.x,yq.y,yq.z,yq.w};
        #pragma unroll
        for (int j=0;j<8;++j)
          #pragma unroll
          for (int oo=0;oo<4;++oo)
            acc[j][oo] += cav[j]*yv[oo];
      }
    }
    __syncthreads();                 // all P2 reads of sh_y complete
    // red overlay on sh_y: red[ng][c][o], 4*16*128 floats = 32 KB
    float* red = sh_y;
    #pragma unroll
    for (int j=0;j<8;++j) {
      float4 w4 = {acc[j][0], acc[j][1], acc[j][2], acc[j][3]};
      *(float4*)&red[(size_t)ng*2048 + (cg*8 + j)*128 + oq*4] = w4;
    }
    __syncthreads();
    // final reduce over ng: thread = (c2 = t>>4, o2 = (t&15)*8)
    const int c2 = t >> 4;
    const int o2 = (t & 15) * 8;
    float4 r0 = {0,0,0,0}, r1 = {0,0,0,0};
    #pragma unroll
    for (int g=0; g<4; ++g) {
      float4 q0 = *(const float4*)&red[(size_t)g*2048 + c2*128 + o2];
      float4 q1 = *(const float4*)&red[(size_t)g*2048 + c2*128 + o2 + 4];
      r0.x += q0.x; r0.y += q0.y; r0.z += q0.z; r0.w += q0.w;
      r1.x += q1.x; r1.y += q1.y; r1.z += q1.z; r1.w += q1.w;
    }
    float* spb = s_part + ((size_t)(b*NCH + ch)*CAPS_ + c2)*OUT_ + o2;
    *(float4*)(spb)     = r0;
    *(float4*)(spb + 4) = r1;
  }
}

// ============================================================
// squash_k: reduce s_part over chunks, squash, write v (or out)
// ============================================================
__global__ __launch_bounds__(128) void squash_k(const float* __restrict__ s_part,
                                                float* __restrict__ out) {
  const int bc = blockIdx.x;       // b*16+c
  const int o  = threadIdx.x;      // 0..127
  const int b = bc >> 4, c = bc & 15;
  const float* sp = s_part + ((size_t)(b*NCH)*CAPS_ + c)*OUT_ + o;
  float s = 0.f;
  #pragma unroll
  for (int ch=0; ch<NCH; ++ch) s += sp[(size_t)ch*CAPS_*OUT_];
  float ss = s*s;
  #pragma unroll
  for (int off=32; off>0; off>>=1) ss += __shfl_down(ss, off, 64);
  __shared__ float red[2];
  if ((o & 63) == 0) red[o>>6] = ss;
  __syncthreads();
  float sn = red[0] + red[1];
  float scale = (sn/(1.f+sn)) / (sqrtf(sn)+1e-8f);
  out[(size_t)bc*OUT_ + o] = scale*s;
}

// ============================================================
extern "C" void kernel_launch(void* const* d_in, const int* in_sizes, int n_in,
                              void* d_out, int out_size, void* d_ws, size_t ws_size,
                              hipStream_t stream) {
  const float* x       = (const float*)d_in[0];
  const float* contrib = (const float*)d_in[1];
  const float* W       = (const float*)d_in[2];
  const float* alpha   = (const float*)d_in[3];
  float* out = (float*)d_out;
  char*  wsb = (char*)d_ws;

  float* y             = (float*)(wsb + Y_BOFF);
  float* logits        = (float*)(wsb + L_BOFF);
  float* v             = (float*)(wsb + V_BOFF);
  float* s_part        = (float*)(wsb + SP_BOFF);
  // bT hi/lo alias the s_part region (consumed before s_part first written)
  unsigned short* bThi = (unsigned short*)(wsb + SP_BOFF);
  unsigned short* bTlo = (unsigned short*)(wsb + SP_BOFF + BT_SZ);

  conv_w<<<N_, 256, 0, stream>>>(W, bThi, bTlo);
  gemm_fn<<<M_/64, 512, 0, stream>>>(x, bThi, bTlo, y);

  route_rs<<<dim3(NCH, B_), 256, 0, stream>>>(y, alpha, contrib, logits, v, s_part, 0);
  squash_k<<<B_*CAPS_, 128, 0, stream>>>(s_part, v);

  for (int it=0; it<3; ++it) {
    route_rs<<<dim3(NCH, B_), 256, 0, stream>>>(y, alpha, contrib, logits, v, s_part, 1);
    squash_k<<<B_*CAPS_, 128, 0, stream>>>(s_part, (it==2) ? out : v);
  }
}

// Round 18
// 128.990 us; speedup vs baseline: 4.0709x; 1.0690x over previous
//
#include <hip/hip_runtime.h>
#include <math.h>

#define B_ 32
#define NODES_ 512
#define IN_ 256
#define OUT_ 128
#define CAPS_ 16
#define KW_ 5
#define M_ (B_*NODES_)            // 16384
#define N_ (KW_*OUT_)             // 640
#define NCH 32                    // node chunks of 16

typedef __attribute__((ext_vector_type(8))) short short8;
typedef __attribute__((ext_vector_type(4))) float f32x4;

// ---- workspace layout (bytes) ---- (round-5 proven: 51,642,368 total)
#define Y_BOFF   0
#define L_BOFF   41943040
#define V_BOFF   42991616
#define SP_BOFF  43253760
#define BT_SZ    (N_*IN_*2)       // 327,680 bytes each

#define YPAD 644                  // 644%32==4 -> 4(nd+2og) start-banks: ~2-way (free)

__device__ __forceinline__ float b2f(unsigned short u) {
  union { unsigned int i; float f; } c; c.i = ((unsigned int)u) << 16; return c.f;
}
__device__ __forceinline__ unsigned short f2b(float f) {
  union { float f; unsigned int i; } c; c.f = f;
  unsigned int u = c.i;
  u += 0x7fffu + ((u >> 16) & 1u);
  return (unsigned short)(u >> 16);
}
__device__ __forceinline__ void async_load16(const void* g, void* l) {
  __builtin_amdgcn_global_load_lds(
      (const __attribute__((address_space(1))) unsigned int*)g,
      (__attribute__((address_space(3))) unsigned int*)l, 16, 0, 0);
}

// ============================================================
// conv_w: split W into K-MAJOR bf16 hi/lo panels.
// ============================================================
__global__ __launch_bounds__(256) void conv_w(const float* __restrict__ W,
                                              unsigned short* __restrict__ bThi,
                                              unsigned short* __restrict__ bTlo) {
  int n = blockIdx.x;           // 0..639
  int i = threadIdx.x;          // 0..255
  int k = n >> 7, o = n & 127;
  float v = W[((size_t)k*IN_ + i)*OUT_ + o];
  unsigned short h = f2b(v);
  size_t dst = ((size_t)(i >> 3)*N_ + n)*8 + (i & 7);
  bThi[dst] = h;
  bTlo[dst] = f2b(v - b2f(h));
}

// ============================================================
// gemm_fn (R10-proven, ~11us): FULL-N blocks, coalesced reg-staged A,
// flat gload_lds B panels, split-bf16 3-pass MFMA.
// ============================================================
__global__ __launch_bounds__(512) void gemm_fn(const float* __restrict__ x,
                                               const unsigned short* __restrict__ bThi,
                                               const unsigned short* __restrict__ bTlo,
                                               float* __restrict__ y) {
  __shared__ float A_lds[8*64*4];      //  8 KB [cg][row][4f]
  __shared__ short Bh_lds[4*640*8];    // 40 KB [kg][n][8]
  __shared__ short Bl_lds[4*640*8];    // 40 KB
  const int t    = threadIdx.x;
  const int w    = t >> 6;
  const int lane = t & 63;
  const int lrow = lane & 15;
  const int lk   = lane >> 4;
  const int m0   = blockIdx.x * 64;
  const int wn0  = w * 80;
  const int arow = t >> 3;
  const int ac4  = t & 7;

  f32x4 acc[4][5];
  #pragma unroll
  for (int i=0;i<4;++i)
    #pragma unroll
    for (int j=0;j<5;++j) acc[i][j] = (f32x4){0.f,0.f,0.f,0.f};

  for (int kbi = 0; kbi < 8; ++kbi) {
    const int kb = kbi*32;
    const unsigned short* bh_src = bThi + (size_t)kbi*4*N_*8;
    const unsigned short* bl_src = bTlo + (size_t)kbi*4*N_*8;
    #pragma unroll
    for (int q=0; q<5; ++q) {
      int db = q*512 + w*64;
      async_load16(bh_src + (size_t)(db + lane)*8, &Bh_lds[db*8]);
      async_load16(bl_src + (size_t)(db + lane)*8, &Bl_lds[db*8]);
    }
    {
      float4 av = *(const float4*)(x + (size_t)(m0 + arow)*IN_ + kb + ac4*4);
      *(float4*)&A_lds[((ac4*64) + arow)*4] = av;
    }
    __syncthreads();

    short8 ah[4], al[4];
    #pragma unroll
    for (int mi=0; mi<4; ++mi) {
      int row = mi*16 + lrow;
      f32x4 a0 = *(const f32x4*)&A_lds[((2*lk  )*64 + row)*4];
      f32x4 a1 = *(const f32x4*)&A_lds[((2*lk+1)*64 + row)*4];
      #pragma unroll
      for (int j=0; j<8; ++j) {
        float f = (j < 4) ? a0[j] : a1[j-4];
        unsigned short h = f2b(f);
        ah[mi][j] = (short)h;
        al[mi][j] = (short)f2b(f - b2f(h));
      }
    }
    #pragma unroll
    for (int ni=0; ni<5; ++ni) {
      int nb = wn0 + ni*16 + lrow;
      short8 bh = *(const short8*)&Bh_lds[(lk*N_ + nb)*8];
      short8 bl = *(const short8*)&Bl_lds[(lk*N_ + nb)*8];
      #pragma unroll
      for (int mi=0; mi<4; ++mi) {
        acc[mi][ni] = __builtin_amdgcn_mfma_f32_16x16x32_bf16(bh, ah[mi], acc[mi][ni], 0, 0, 0);
        acc[mi][ni] = __builtin_amdgcn_mfma_f32_16x16x32_bf16(bh, al[mi], acc[mi][ni], 0, 0, 0);
        acc[mi][ni] = __builtin_amdgcn_mfma_f32_16x16x32_bf16(bl, ah[mi], acc[mi][ni], 0, 0, 0);
      }
    }
    __syncthreads();
  }

  #pragma unroll
  for (int mi=0; mi<4; ++mi) {
    int m = m0 + mi*16 + lrow;
    #pragma unroll
    for (int ni=0; ni<5; ++ni) {
      int nb = wn0 + ni*16 + lk*4;
      float4 o = {acc[mi][ni][0], acc[mi][ni][1], acc[mi][ni][2], acc[mi][ni][3]};
      *(float4*)(y + (size_t)m*N_ + nb) = o;
    }
  }
}

// ============================================================
// route_rs (R17 + 2 fixes): distinct-lane LDS reads in both phases.
// Fix 1: phase-1 cap-reduce = butterfly REDUCE-SCATTER (15 shfl +
//        30 cndmask, was 64 shfl all-reduce). Lane og ends with cap og.
// Fix 2: YPAD 648->644 (~2-way banks both phases, was 4-way).
// ============================================================
__global__ __launch_bounds__(256) void route_rs(const float* __restrict__ y,
                                                const float* __restrict__ alpha,
                                                const float* __restrict__ contrib,
                                                float* __restrict__ logits,
                                                const float* __restrict__ vin,
                                                float* __restrict__ s_part,
                                                int mode) {
  __shared__ __align__(16) float sh_y[16*YPAD];   // 41.2 KB (red overlay after P2)
  __shared__ __align__(16) float sh_v[16*132];    //  8.4 KB [cap][o]
  __shared__ __align__(16) float sh_aT[16*80];    //  5 KB  [nd][k*16+c]
  __shared__ __align__(16) float sh_cwa[16*80];   //  5 KB  [nd][k*16+c]
  __shared__ float sh_cw[256];                    //  1 KB  [nd*16+c]

  const int t  = threadIdx.x;
  const int ch = blockIdx.x;   // 0..31
  const int b  = blockIdx.y;   // 0..31
  const int n0 = ch*16;

  // ---- stage y: reg round-trip into padded rows ----
  const float* ybase = y + ((size_t)(b*NODES_ + n0))*N_;
  float4 yst[10];
  #pragma unroll
  for (int q=0; q<10; ++q) yst[q] = *(const float4*)(ybase + (size_t)(t + q*256)*4);
  #pragma unroll
  for (int q=0; q<10; ++q) {
    int flat = (t + q*256)*4;
    int nd   = flat / 640;
    int rem  = flat - nd*640;
    *(float4*)&sh_y[nd*YPAD + rem] = yst[q];
  }
  // ---- stage alpha TRANSPOSED: aT[nd][k*16+c] = alpha[n0+nd][c][k] ----
  const float* abase = alpha + (size_t)n0*CAPS_*KW_;
  for (int i = t; i < 320; i += 256) {
    float4 av = *(const float4*)(abase + i*4);
    int flat = i*4;
    int nd   = flat / 80;
    int rem  = flat - nd*80;
    #pragma unroll
    for (int e=0; e<4; ++e) {
      int r = rem + e;
      int c = r / 5;
      int k = r - c*5;
      sh_aT[nd*80 + k*16 + c] = av[e];
    }
  }
  if (mode >= 1) {
    const float* vbase = vin + (size_t)b*CAPS_*OUT_;
    #pragma unroll
    for (int q=0; q<2; ++q) {
      int flat = (t + q*256)*4;
      int c = flat >> 7, o = flat & 127;
      float4 vv = *(const float4*)(vbase + flat);
      *(float4*)&sh_v[c*132 + o] = vv;
    }
  } else {
    sh_cw[t] = 0.0625f;
    int nd = t >> 4, c = t & 15;
    logits[((size_t)b*CAPS_ + c)*NODES_ + n0 + nd] = contrib[(size_t)b*NODES_ + n0 + nd];
  }
  __syncthreads();

  if (mode >= 1) {
    // ---- phase 1: thread = (nd = t>>4, og = t&15), o-range og*8..+7 ----
    const int nd = t >> 4, og = t & 15;
    float4 yq[5][2];
    #pragma unroll
    for (int k=0; k<5; ++k) {
      yq[k][0] = *(const float4*)&sh_y[nd*YPAD + k*128 + og*8];
      yq[k][1] = *(const float4*)&sh_y[nd*YPAD + k*128 + og*8 + 4];
    }
    float p[16];
    #pragma unroll
    for (int c=0;c<16;++c) p[c] = 0.f;
    #pragma unroll
    for (int cq=0; cq<4; ++cq) {
      float4 a5[5];
      #pragma unroll
      for (int k=0;k<5;++k) a5[k] = *(const float4*)&sh_aT[nd*80 + k*16 + cq*4];
      #pragma unroll
      for (int cl=0; cl<4; ++cl) {
        int c = cq*4 + cl;
        float4 v0 = *(const float4*)&sh_v[c*132 + og*8];
        float4 v1 = *(const float4*)&sh_v[c*132 + og*8 + 4];
        float d[5];
        #pragma unroll
        for (int k=0;k<5;++k) {
          d[k] = yq[k][0].x*v0.x + yq[k][0].y*v0.y + yq[k][0].z*v0.z + yq[k][0].w*v0.w
               + yq[k][1].x*v1.x + yq[k][1].y*v1.y + yq[k][1].z*v1.z + yq[k][1].w*v1.w;
        }
        p[c] += a5[0][cl]*d[0] + a5[1][cl]*d[1] + a5[2][cl]*d[2]
              + a5[3][cl]*d[3] + a5[4][cl]*d[4];
      }
    }
    // ---- butterfly REDUCE-SCATTER over 16 og-lanes: lane og -> cap og ----
    float q8[8];
    #pragma unroll
    for (int j=0;j<8;++j) {
      float a = p[2*j], bb = p[2*j+1];
      float mine = (og & 1) ? bb : a;
      float othr = (og & 1) ? a  : bb;
      q8[j] = mine + __shfl_xor(othr, 1, 64);
    }
    float r4[4];
    #pragma unroll
    for (int j=0;j<4;++j) {
      float a = q8[2*j], bb = q8[2*j+1];
      float mine = (og & 2) ? bb : a;
      float othr = (og & 2) ? a  : bb;
      r4[j] = mine + __shfl_xor(othr, 2, 64);
    }
    float s2[2];
    #pragma unroll
    for (int j=0;j<2;++j) {
      float a = r4[2*j], bb = r4[2*j+1];
      float mine = (og & 4) ? bb : a;
      float othr = (og & 4) ? a  : bb;
      s2[j] = mine + __shfl_xor(othr, 4, 64);
    }
    float aa = s2[0], bb2 = s2[1];
    float mine4 = (og & 8) ? bb2 : aa;
    float othr4 = (og & 8) ? aa  : bb2;
    float fin = mine4 + __shfl_xor(othr4, 8, 64);

    float lold = logits[((size_t)b*CAPS_ + og)*NODES_ + n0 + nd];
    float newl = lold + fin;
    logits[((size_t)b*CAPS_ + og)*NODES_ + n0 + nd] = newl;
    // softmax over caps (= og lanes of same nd)
    float m = newl;
    m = fmaxf(m, __shfl_xor(m, 1, 64));
    m = fmaxf(m, __shfl_xor(m, 2, 64));
    m = fmaxf(m, __shfl_xor(m, 4, 64));
    m = fmaxf(m, __shfl_xor(m, 8, 64));
    float e = __expf(newl - m);
    float ssum = e;
    ssum += __shfl_xor(ssum, 1, 64);
    ssum += __shfl_xor(ssum, 2, 64);
    ssum += __shfl_xor(ssum, 4, 64);
    ssum += __shfl_xor(ssum, 8, 64);
    sh_cw[nd*16 + og] = e / ssum;
  }
  __syncthreads();

  // ---- cwa[nd][k*16+c] = cw[nd][c] * aT ----
  #pragma unroll
  for (int i = t; i < 1280; i += 256) {
    int nd = i / 80;
    int c  = i & 15;               // i%80's low 4 bits == c (16 | 80 layout)
    sh_cwa[i] = sh_cw[nd*16 + c] * sh_aT[i];
  }
  __syncthreads();

  // ---- phase 2: thread = (oq = t&31, cg = (t>>5)&1, ng = t>>6) ----
  {
    const int oq = t & 31;
    const int cg = (t >> 5) & 1;
    const int ng = t >> 6;          // wave id; nds {ng, ng+4, ng+8, ng+12}
    float acc[8][4];
    #pragma unroll
    for (int j=0;j<8;++j)
      #pragma unroll
      for (int oo=0;oo<4;++oo) acc[j][oo] = 0.f;

    #pragma unroll
    for (int ii=0; ii<4; ++ii) {
      int nd = ng + ii*4;
      #pragma unroll
      for (int k=0; k<5; ++k) {
        float4 yq  = *(const float4*)&sh_y[nd*YPAD + k*128 + oq*4];
        float4 ca0 = *(const float4*)&sh_cwa[nd*80 + k*16 + cg*8];
        float4 ca1 = *(const float4*)&sh_cwa[nd*80 + k*16 + cg*8 + 4];
        float cav[8] = {ca0.x,ca0.y,ca0.z,ca0.w,ca1.x,ca1.y,ca1.z,ca1.w};
        float yv[4]  = {yq.x,yq.y,yq.z,yq.w};
        #pragma unroll
        for (int j=0;j<8;++j)
          #pragma unroll
          for (int oo=0;oo<4;++oo)
            acc[j][oo] += cav[j]*yv[oo];
      }
    }
    __syncthreads();                 // all P2 reads of sh_y complete
    // red overlay on sh_y: red[ng][c][o], 4*16*128 floats = 32 KB
    float* red = sh_y;
    #pragma unroll
    for (int j=0;j<8;++j) {
      float4 w4 = {acc[j][0], acc[j][1], acc[j][2], acc[j][3]};
      *(float4*)&red[(size_t)ng*2048 + (cg*8 + j)*128 + oq*4] = w4;
    }
    __syncthreads();
    // final reduce over ng: thread = (c2 = t>>4, o2 = (t&15)*8)
    const int c2 = t >> 4;
    const int o2 = (t & 15) * 8;
    float4 r0 = {0,0,0,0}, r1 = {0,0,0,0};
    #pragma unroll
    for (int g=0; g<4; ++g) {
      float4 q0 = *(const float4*)&red[(size_t)g*2048 + c2*128 + o2];
      float4 q1 = *(const float4*)&red[(size_t)g*2048 + c2*128 + o2 + 4];
      r0.x += q0.x; r0.y += q0.y; r0.z += q0.z; r0.w += q0.w;
      r1.x += q1.x; r1.y += q1.y; r1.z += q1.z; r1.w += q1.w;
    }
    float* spb = s_part + ((size_t)(b*NCH + ch)*CAPS_ + c2)*OUT_ + o2;
    *(float4*)(spb)     = r0;
    *(float4*)(spb + 4) = r1;
  }
}

// ============================================================
// squash_k: reduce s_part over chunks, squash, write v (or out)
// ============================================================
__global__ __launch_bounds__(128) void squash_k(const float* __restrict__ s_part,
                                                float* __restrict__ out) {
  const int bc = blockIdx.x;       // b*16+c
  const int o  = threadIdx.x;      // 0..127
  const int b = bc >> 4, c = bc & 15;
  const float* sp = s_part + ((size_t)(b*NCH)*CAPS_ + c)*OUT_ + o;
  float s = 0.f;
  #pragma unroll
  for (int ch=0; ch<NCH; ++ch) s += sp[(size_t)ch*CAPS_*OUT_];
  float ss = s*s;
  #pragma unroll
  for (int off=32; off>0; off>>=1) ss += __shfl_down(ss, off, 64);
  __shared__ float red[2];
  if ((o & 63) == 0) red[o>>6] = ss;
  __syncthreads();
  float sn = red[0] + red[1];
  float scale = (sn/(1.f+sn)) / (sqrtf(sn)+1e-8f);
  out[(size_t)bc*OUT_ + o] = scale*s;
}

// ============================================================
extern "C" void kernel_launch(void* const* d_in, const int* in_sizes, int n_in,
                              void* d_out, int out_size, void* d_ws, size_t ws_size,
                              hipStream_t stream) {
  const float* x       = (const float*)d_in[0];
  const float* contrib = (const float*)d_in[1];
  const float* W       = (const float*)d_in[2];
  const float* alpha   = (const float*)d_in[3];
  float* out = (float*)d_out;
  char*  wsb = (char*)d_ws;

  float* y             = (float*)(wsb + Y_BOFF);
  float* logits        = (float*)(wsb + L_BOFF);
  float* v             = (float*)(wsb + V_BOFF);
  float* s_part        = (float*)(wsb + SP_BOFF);
  // bT hi/lo alias the s_part region (consumed before s_part first written)
  unsigned short* bThi = (unsigned short*)(wsb + SP_BOFF);
  unsigned short* bTlo = (unsigned short*)(wsb + SP_BOFF + BT_SZ);

  conv_w<<<N_, 256, 0, stream>>>(W, bThi, bTlo);
  gemm_fn<<<M_/64, 512, 0, stream>>>(x, bThi, bTlo, y);

  route_rs<<<dim3(NCH, B_), 256, 0, stream>>>(y, alpha, contrib, logits, v, s_part, 0);
  squash_k<<<B_*CAPS_, 128, 0, stream>>>(s_part, v);

  for (int it=0; it<3; ++it) {
    route_rs<<<dim3(NCH, B_), 256, 0, stream>>>(y, alpha, contrib, logits, v, s_part, 1);
    squash_k<<<B_*CAPS_, 128, 0, stream>>>(s_part, (it==2) ? out : v);
  }
}